// Round 17
// baseline (137.572 us; speedup 1.0000x reference)
//
#include <hip/hip_runtime.h>
#include <math.h>

constexpr int D    = 128;
constexpr int BT   = 128;    // targets per sort bucket (bucket = tgt >> 7)
constexpr int BTS  = 64;     // targets per gather block (sub-bucket)
constexpr int TILE = 4096;   // edges per bucketize block
constexpr int CE   = 256;    // edges per gather chunk

using bf16x8 = __attribute__((ext_vector_type(8))) short;
using f32x4  = __attribute__((ext_vector_type(4))) float;
using f32x2  = __attribute__((ext_vector_type(2))) float;
#define MFMA16 __builtin_amdgcn_mfma_f32_16x16x32_bf16

__device__ __forceinline__ unsigned short f2bf(float f) {
    unsigned u = __builtin_bit_cast(unsigned, f);
    u = (u + 0x7FFF + ((u >> 16) & 1)) >> 16;   // RNE
    return (unsigned short)u;
}

// ---------------------------------------------------------------------------
// Kernel A: wprod (blocks 0..15) || prep (blocks 16..). (r15/r16, verified)
// ---------------------------------------------------------------------------
__global__ __launch_bounds__(256)
void prepA_kernel(const float* __restrict__ Wl, const float* __restrict__ Wr,
                  const float* __restrict__ Wp,
                  const float* __restrict__ bl, const float* __restrict__ bp,
                  unsigned short* __restrict__ WlpB, unsigned short* __restrict__ WrpB,
                  float* __restrict__ cvec,
                  const int* __restrict__ ea, int Ea,
                  const int* __restrict__ eb, int Eb,
                  unsigned int* __restrict__ ent_a, int* __restrict__ cnt_a,
                  unsigned int* __restrict__ ent_b, int* __restrict__ cnt_b,
                  int NBKT, int CAP, int GA)
{
    __shared__ float wm[128 * 129];   // wprod branch
    __shared__ float wpc[128 * 16];
    __shared__ int hist[512];         // prep branch
    __shared__ int base[512];

    const int bid = blockIdx.x;
    const int t   = threadIdx.x;

    if (bid < 16) {
        const int m   = bid >> 3;
        const int cg  = bid & 7;
        const int c0  = cg * 16;
        const float* Wm = m ? Wr : Wl;
        unsigned short* OB = m ? WrpB : WlpB;

        for (int i = t; i < 128 * 128; i += 256) {
            int r = i >> 7, k = i & 127;
            wm[r * 129 + k] = Wm[i];
        }
        for (int i = t; i < 2048; i += 256) {
            int k = i >> 4, col = i & 15;
            wpc[i] = Wp[k * 128 + c0 + col];
        }
        __syncthreads();

        const int r = t >> 1;
        const int h = (t & 1) * 8;
        float acc[8];
        #pragma unroll
        for (int j = 0; j < 8; ++j) acc[j] = 0.f;

        for (int k = 0; k < 128; ++k) {
            float wv = wm[r * 129 + k];
            #pragma unroll
            for (int j = 0; j < 8; ++j) acc[j] += wv * wpc[k * 16 + h + j];
        }

        const int kt = r >> 5, lhi = (r >> 3) & 3, jj = r & 7;
        #pragma unroll
        for (int j = 0; j < 8; ++j) {
            int l = lhi * 16 + h + j;
            OB[((size_t)(kt * 8 + cg) * 64 + l) * 8 + jj] = f2bf(acc[j]);
        }

        if (m == 0 && t < 16) {
            int c = c0 + t;
            float s = bp[c];
            for (int k = 0; k < 128; ++k) s += bl[k] * wpc[k * 16 + t];
            cvec[c] = s;
        }
    } else {
        const int pb   = bid - 16;
        const int type = (pb >= GA);
        const int* e   = type ? eb : ea;
        const int  E   = type ? Eb : Ea;
        unsigned int* ent = type ? ent_b : ent_a;
        int* cnt          = type ? cnt_b : cnt_a;
        const int i0 = (pb - type * GA) * TILE;

        for (int h = t; h < NBKT; h += 256) hist[h] = 0;
        __syncthreads();

        int tgts[16];
        #pragma unroll
        for (int j = 0; j < 16; ++j) {
            int i = i0 + j * 256 + t;
            tgts[j] = (i < E) ? e[(size_t)E + i] : -1;
            if (tgts[j] >= 0) atomicAdd(&hist[tgts[j] >> 7], 1);
        }
        __syncthreads();

        for (int h = t; h < NBKT; h += 256) {
            base[h] = (hist[h] > 0) ? atomicAdd(&cnt[h], hist[h]) : 0;
            hist[h] = 0;
        }
        __syncthreads();

        #pragma unroll
        for (int j = 0; j < 16; ++j) {
            int i = i0 + j * 256 + t;
            if (tgts[j] >= 0) {
                int b   = tgts[j] >> 7;
                int pos = base[b] + atomicAdd(&hist[b], 1);
                if (pos < CAP)
                    ent[(size_t)b * CAP + pos] = ((unsigned)e[i] << 7) | (tgts[j] & 127);
            }
        }
    }
}

// ---------------------------------------------------------------------------
// Kernel B: sort (blocks 0..2*NBKT-1) || gemmz (rest). (r15/r16, verified)
// ---------------------------------------------------------------------------
__global__ __launch_bounds__(512)
void sortB_kernel(const unsigned int* __restrict__ ent_a, const int* __restrict__ cnt_a,
                  const unsigned int* __restrict__ ent_b, const int* __restrict__ cnt_b,
                  unsigned short* __restrict__ srcl_g, int* __restrict__ off_g,
                  const float* __restrict__ x,
                  const unsigned short* __restrict__ WlpB,
                  const unsigned short* __restrict__ WrpB,
                  const float* __restrict__ cvec,
                  unsigned short* __restrict__ zl, unsigned short* __restrict__ zr,
                  int N, int NBKT, int CAP)
{
    extern __shared__ __align__(16) char smem_raw[];

    const int bid = blockIdx.x;
    const int t   = threadIdx.x;

    if (bid < 2 * NBKT) {
        int* tmp  = (int*)smem_raw;                          // CAP
        int* off  = tmp + CAP;                               // BT+1
        int* cur  = off + BT + 1;                            // BT
        int* wtot = cur + BT;                                // 2
        unsigned short* srcl = (unsigned short*)(wtot + 2);  // CAP

        const int type = (bid >= NBKT);
        const int k    = bid - type * NBKT;
        const unsigned int* ent = type ? ent_b : ent_a;
        const int cnt = min((type ? cnt_b : cnt_a)[k], CAP);
        const int l = t & 63, w = t >> 6;

        if (t < BT) off[t] = 0;
        __syncthreads();

        for (int i = t; i < cnt; i += 512) {
            unsigned e = ent[(size_t)k * CAP + i];
            tmp[i] = (int)e;
            atomicAdd(&off[e & (BT - 1)], 1);
        }
        __syncthreads();

        int v = 0, s = 0;
        if (t < BT) {
            v = off[t]; s = v;
            #pragma unroll
            for (int o = 1; o < 64; o <<= 1) {
                int u = __shfl_up(s, o, 64);
                if (l >= o) s += u;
            }
            if (l == 63) wtot[w] = s;
        }
        __syncthreads();
        if (t < BT) {
            int ex = ((w == 1) ? wtot[0] : 0) + s - v;
            off[t] = ex; cur[t] = ex;
        }
        if (t == 0) off[BT] = wtot[0] + wtot[1];
        __syncthreads();

        for (int i = t; i < cnt; i += 512) {
            unsigned e = (unsigned)tmp[i];
            int pos = atomicAdd(&cur[e & (BT - 1)], 1);
            srcl[pos] = (unsigned short)(e >> 7);
        }
        __syncthreads();

        for (int i = t; i < cnt; i += 512)
            srcl_g[(size_t)bid * CAP + i] = srcl[i];
        if (t <= BT)
            off_g[(size_t)bid * (BT + 1) + t] = off[t];
    } else {
        const int gb = bid - 2 * NBKT;
        const int w = t >> 6, l = t & 63;
        const int q = l & 15, kg = l >> 4;
        const int node0 = gb * 128 + w * 16;
        const int arow = min(node0 + q, N - 1);

        const float4* xp = reinterpret_cast<const float4*>(x + (size_t)arow * D);
        bf16x8 fx[4];
        #pragma unroll
        for (int kt = 0; kt < 4; ++kt) {
            float4 a = xp[kt * 8 + kg * 2];
            float4 b = xp[kt * 8 + kg * 2 + 1];
            bf16x8 f;
            f[0] = (short)f2bf(a.x); f[1] = (short)f2bf(a.y);
            f[2] = (short)f2bf(a.z); f[3] = (short)f2bf(a.w);
            f[4] = (short)f2bf(b.x); f[5] = (short)f2bf(b.y);
            f[6] = (short)f2bf(b.z); f[7] = (short)f2bf(b.w);
            fx[kt] = f;
        }

        #pragma unroll
        for (int nt = 0; nt < 8; ++nt) {
            f32x4 cl = {0.f, 0.f, 0.f, 0.f};
            f32x4 cr = {0.f, 0.f, 0.f, 0.f};
            #pragma unroll
            for (int kt = 0; kt < 4; ++kt) {
                const size_t fo = ((size_t)(kt * 8 + nt) * 64 + l) * 8;
                bf16x8 wl = *reinterpret_cast<const bf16x8*>(WlpB + fo);
                bf16x8 wr = *reinterpret_cast<const bf16x8*>(WrpB + fo);
                cl = MFMA16(fx[kt], wl, cl, 0, 0, 0);
                cr = MFMA16(fx[kt], wr, cr, 0, 0, 0);
            }
            float cv = cvec[nt * 16 + q];
            const int sidx = nt >> 1;
            const int cin  = (nt & 1) * 16 + q;
            #pragma unroll
            for (int r = 0; r < 4; ++r) {
                int grow = node0 + kg * 4 + r;
                if (grow < N) {
                    zl[((size_t)sidx * (N + 1) + grow) * 32 + cin] = f2bf(cl[r]);
                    zr[(size_t)grow * D + nt * 16 + q]             = f2bf(cr[r] + cv);
                }
            }
        }
    }
}

// ---------------------------------------------------------------------------
// gather v9: 512-thread blocks, BTS=64, CE=256 double-buffer (2x16KB LDS).
// 4 blocks/CU x 512 thr = 2048 = FULL thread occupancy (r12's CE=256 failed
// only because 256-thr blocks gave 1024 thr/CU). Barriers per edge HALVE vs
// r16; same one-target-per-8-lane-group consume, counted vmcnt(2),
// global_load_lds staging, slice=bid&3 XCD residency (FETCH ~22MB, r5-r16).
// ---------------------------------------------------------------------------
__global__ __launch_bounds__(512)
void gather_kernel(const unsigned short* __restrict__ zl,   // [4][N+1][32]
                   const unsigned short* __restrict__ srcl_g,
                   const int* __restrict__ off_g,
                   unsigned short* __restrict__ agg_a,
                   unsigned short* __restrict__ agg_b,
                   int N, int NBKT, int CAP)
{
    __shared__ int off[BTS + 1];
    __shared__ unsigned short stage[2][CE * 32];   // 2 x 16 KB

    const int bid   = blockIdx.x;
    const int slice = bid & 3;
    const int rest  = bid >> 2;
    const int sb    = rest & 1;                // sub-bucket 0..1
    const int tb    = rest >> 1;               // (type, k128)
    const int type  = (tb >= NBKT);
    const int k     = tb - type * NBKT;

    const int t = threadIdx.x, l = t & 63, w = t >> 6;   // 8 waves
    const int tg = l >> 3;                     // group 0..7
    const int c8 = l & 7;                      // uint2 within 64B row

    for (int i = t; i <= BTS; i += 512)
        off[i] = off_g[(size_t)tb * (BT + 1) + sb * BTS + i];
    __syncthreads();

    const int base0 = off[0];
    const int cnt   = off[BTS] - base0;
    const unsigned short* zs = zl + (size_t)slice * (N + 1) * 32;
    const unsigned short* sl = srcl_g + (size_t)tb * CAP;

    const int tt = w * 8 + tg;                 // my single target (0..63)
    const int o0 = off[tt], o1 = off[tt + 1];
    f32x2 aP = {0.f, 0.f}, aQ = {0.f, 0.f};

    const int nc = (cnt + CE - 1) / CE;

#define STAGE(cc, bb)                                                         \
    {                                                                         \
        const int _c0 = base0 + (cc) * CE;                                    \
        _Pragma("unroll")                                                     \
        for (int i = 0; i < 2; ++i) {                                         \
            const int el = w * 32 + i * 16 + (l >> 2);                        \
            const unsigned sid = sl[_c0 + el];                                \
            const char* g = (const char*)zs + (size_t)sid * 64 + (l & 3) * 16;\
            char* ldsb = (char*)stage[bb] + (size_t)(w * 32 + i * 16) * 64;   \
            __builtin_amdgcn_global_load_lds(                                 \
                (const __attribute__((address_space(1))) unsigned*)g,         \
                (__attribute__((address_space(3))) unsigned*)ldsb, 16, 0, 0); \
        }                                                                     \
    }

    if (nc > 0) STAGE(0, 0);

    for (int c = 0; c < nc; ++c) {
        if (c + 1 < nc) {
            STAGE(c + 1, (c + 1) & 1);
            asm volatile("s_waitcnt vmcnt(2)" ::: "memory");
        } else {
            asm volatile("s_waitcnt vmcnt(0)" ::: "memory");
        }
        __builtin_amdgcn_s_barrier();
        asm volatile("" ::: "memory");

        const int c0 = base0 + c * CE;
        const unsigned short* sg = stage[c & 1];
        const int lo = max(o0, c0);
        const int hi = min(o1, c0 + CE);
        int j = lo;
        for (; j + 1 < hi; j += 2) {
            uint2 v0 = *reinterpret_cast<const uint2*>(sg + (j - c0) * 32 + c8 * 4);
            uint2 v1 = *reinterpret_cast<const uint2*>(sg + (j + 1 - c0) * 32 + c8 * 4);
            f32x2 p0, q0, p1, q1;
            p0[0] = __builtin_bit_cast(float, v0.x << 16);
            p0[1] = __builtin_bit_cast(float, v0.y << 16);
            q0[0] = __builtin_bit_cast(float, v0.x & 0xffff0000u);
            q0[1] = __builtin_bit_cast(float, v0.y & 0xffff0000u);
            p1[0] = __builtin_bit_cast(float, v1.x << 16);
            p1[1] = __builtin_bit_cast(float, v1.y << 16);
            q1[0] = __builtin_bit_cast(float, v1.x & 0xffff0000u);
            q1[1] = __builtin_bit_cast(float, v1.y & 0xffff0000u);
            aP += p0 + p1;
            aQ += q0 + q1;
        }
        if (j < hi) {
            uint2 v0 = *reinterpret_cast<const uint2*>(sg + (j - c0) * 32 + c8 * 4);
            f32x2 p0, q0;
            p0[0] = __builtin_bit_cast(float, v0.x << 16);
            p0[1] = __builtin_bit_cast(float, v0.y << 16);
            q0[0] = __builtin_bit_cast(float, v0.x & 0xffff0000u);
            q0[1] = __builtin_bit_cast(float, v0.y & 0xffff0000u);
            aP += p0;
            aQ += q0;
        }
        asm volatile("" ::: "memory");
        __builtin_amdgcn_s_barrier();   // stage[c&1] free before c+1 overwrites
    }
#undef STAGE

    unsigned short* agg = (type ? agg_b : agg_a) + (size_t)slice * N * 32;
    const int n = k * BT + sb * BTS + tt;
    const int deg = o1 - o0;
    if (n < N) {
        const float r = 1.0f / fmaxf((float)deg, 1.0f);
        uint2 o;
        o.x = ((unsigned)f2bf(aQ[0] * r) << 16) | f2bf(aP[0] * r);
        o.y = ((unsigned)f2bf(aQ[1] * r) << 16) | f2bf(aP[1] * r);
        *reinterpret_cast<uint2*>(agg + (size_t)n * 32 + c8 * 4) = o;
    }
}

// ---------------------------------------------------------------------------
// epilogue: logits_t = agg_t + Z_r; softmax, average, store f32. (verified r9)
// ---------------------------------------------------------------------------
__global__ __launch_bounds__(256)
void epi_kernel(const unsigned short* __restrict__ agg_a,
                const unsigned short* __restrict__ agg_b,
                const unsigned short* __restrict__ zr,
                float* __restrict__ out, int N)
{
    const int t = threadIdx.x;
    const int n = blockIdx.x * 16 + (t >> 4);
    const int c = t & 15;
    if (n >= N) return;

    const int s = c >> 2;
    const size_t aoff = ((size_t)s * N + n) * 32 + (c & 3) * 8;
    uint4 va = *reinterpret_cast<const uint4*>(agg_a + aoff);
    uint4 vb = *reinterpret_cast<const uint4*>(agg_b + aoff);
    uint4 vz = *reinterpret_cast<const uint4*>(zr + (size_t)n * D + c * 8);

    unsigned ua[4] = {va.x, va.y, va.z, va.w};
    unsigned ub[4] = {vb.x, vb.y, vb.z, vb.w};
    unsigned uz[4] = {vz.x, vz.y, vz.z, vz.w};

    float la[8], lb[8];
    #pragma unroll
    for (int d = 0; d < 4; ++d) {
        float z0 = __builtin_bit_cast(float, uz[d] << 16);
        float z1 = __builtin_bit_cast(float, uz[d] & 0xffff0000u);
        la[2*d]   = __builtin_bit_cast(float, ua[d] << 16) + z0;
        la[2*d+1] = __builtin_bit_cast(float, ua[d] & 0xffff0000u) + z1;
        lb[2*d]   = __builtin_bit_cast(float, ub[d] << 16) + z0;
        lb[2*d+1] = __builtin_bit_cast(float, ub[d] & 0xffff0000u) + z1;
    }

    float ma = -INFINITY, mb = -INFINITY;
    #pragma unroll
    for (int j = 0; j < 8; ++j) { ma = fmaxf(ma, la[j]); mb = fmaxf(mb, lb[j]); }
    #pragma unroll
    for (int o = 1; o < 16; o <<= 1) {
        ma = fmaxf(ma, __shfl_xor(ma, o, 64));
        mb = fmaxf(mb, __shfl_xor(mb, o, 64));
    }
    float sa = 0.f, sb = 0.f;
    #pragma unroll
    for (int j = 0; j < 8; ++j) {
        la[j] = __expf(la[j] - ma); sa += la[j];
        lb[j] = __expf(lb[j] - mb); sb += lb[j];
    }
    #pragma unroll
    for (int o = 1; o < 16; o <<= 1) {
        sa += __shfl_xor(sa, o, 64);
        sb += __shfl_xor(sb, o, 64);
    }
    const float ra = 0.5f / sa, rb = 0.5f / sb;

    float4 o0, o1;
    o0.x = la[0]*ra + lb[0]*rb; o0.y = la[1]*ra + lb[1]*rb;
    o0.z = la[2]*ra + lb[2]*rb; o0.w = la[3]*ra + lb[3]*rb;
    o1.x = la[4]*ra + lb[4]*rb; o1.y = la[5]*ra + lb[5]*rb;
    o1.z = la[6]*ra + lb[6]*rb; o1.w = la[7]*ra + lb[7]*rb;
    float* op = out + (size_t)n * D + c * 8;
    *reinterpret_cast<float4*>(op)     = o0;
    *reinterpret_cast<float4*>(op + 4) = o1;
}

// ---------------------------------------------------------------------------
extern "C" void kernel_launch(void* const* d_in, const int* in_sizes, int n_in,
                              void* d_out, int out_size, void* d_ws, size_t ws_size,
                              hipStream_t stream)
{
    const float* x  = (const float*)d_in[0];
    const float* Wl = (const float*)d_in[1];
    const float* bl = (const float*)d_in[2];
    const float* Wr = (const float*)d_in[3];
    const float* Wp = (const float*)d_in[4];
    const float* bp = (const float*)d_in[5];
    const int*   ea = (const int*)d_in[6];
    const int*   eb = (const int*)d_in[7];

    const int N  = in_sizes[0] / D;
    const int Ea = in_sizes[6] / 2;
    const int Eb = in_sizes[7] / 2;

    const int NBKT = (N + BT - 1) / BT;          // 391 for N=50000
    const int Emax = Ea > Eb ? Ea : Eb;
    int CAP = (int)(((long long)Emax * BT / N) * 5 / 4 + 128);   // ~2688
    CAP = (CAP + 7) & ~7;

    unsigned int* ent_a = (unsigned int*)d_ws;              // NBKT*CAP
    unsigned int* ent_b = ent_a + (size_t)NBKT * CAP;
    int* cnt_a = (int*)(ent_b + (size_t)NBKT * CAP);        // NBKT
    int* cnt_b = cnt_a + NBKT;
    int* off_g = cnt_b + NBKT;                              // 2*NBKT*(BT+1)
    float* cvec = (float*)(off_g + (size_t)2 * NBKT * (BT + 1));  // 128
    uintptr_t p = (uintptr_t)(cvec + 128);
    p = (p + 15) & ~(uintptr_t)15;
    unsigned short* srcl_g = (unsigned short*)p;            // 2*NBKT*CAP + slack
    unsigned short* zl     = srcl_g + (size_t)2 * NBKT * CAP + 1024; // [4][N+1][32]
    unsigned short* zr     = zl + (size_t)4 * (N + 1) * 32;
    unsigned short* agg_a  = zr + (size_t)N * D;            // [4][N][32]
    unsigned short* agg_b  = agg_a + (size_t)N * D;
    unsigned short* WlpB   = agg_b + (size_t)N * D;
    unsigned short* WrpB   = WlpB + D * D;

    hipMemsetAsync(cnt_a, 0, sizeof(int) * 2 * (size_t)NBKT, stream);

    const int GA = (Ea + TILE - 1) / TILE;
    const int GB = (Eb + TILE - 1) / TILE;

    // Kernel A: wprod (16 blocks) || prep (GA+GB blocks)
    prepA_kernel<<<16 + GA + GB, 256, 0, stream>>>(
        Wl, Wr, Wp, bl, bp, WlpB, WrpB, cvec,
        ea, Ea, eb, Eb, ent_a, cnt_a, ent_b, cnt_b, NBKT, CAP, GA);

    // Kernel B: sort (2*NBKT blocks) || gemmz (ceil(N/128) blocks)
    const int GZ = (N + 127) / 128;
    const int smem_sort = CAP * 6 + (BT + 1 + BT + 2) * 4 + 16;
    sortB_kernel<<<2 * NBKT + GZ, 512, smem_sort, stream>>>(
        ent_a, cnt_a, ent_b, cnt_b, srcl_g, off_g,
        x, WlpB, WrpB, cvec, zl, zr, N, NBKT, CAP);

    // gather: 2*NBKT buckets x 2 sub-buckets x 4 slices; slice = bid&3
    gather_kernel<<<2 * NBKT * 2 * 4, 512, 0, stream>>>(
        zl, srcl_g, off_g, agg_a, agg_b, N, NBKT, CAP);

    epi_kernel<<<(N + 15) / 16, 256, 0, stream>>>(agg_a, agg_b, zr,
                                                  (float*)d_out, N);
}

// Round 18
// 134.109 us; speedup vs baseline: 1.0258x; 1.0258x over previous
//
#include <hip/hip_runtime.h>
#include <math.h>

constexpr int D    = 128;
constexpr int BT   = 128;    // targets per sort bucket (bucket = tgt >> 7)
constexpr int BTS  = 32;     // targets per gather block (sub-bucket)
constexpr int TILE = 4096;   // edges per bucketize block
constexpr int CE   = 128;    // edges per gather chunk

using bf16x8 = __attribute__((ext_vector_type(8))) short;
using f32x4  = __attribute__((ext_vector_type(4))) float;
using f32x2  = __attribute__((ext_vector_type(2))) float;
#define MFMA16 __builtin_amdgcn_mfma_f32_16x16x32_bf16

__device__ __forceinline__ unsigned short f2bf(float f) {
    unsigned u = __builtin_bit_cast(unsigned, f);
    u = (u + 0x7FFF + ((u >> 16) & 1)) >> 16;   // RNE
    return (unsigned short)u;
}

// ---------------------------------------------------------------------------
// Kernel A: wprod (blocks 0..15) || prep (blocks 16..). (r15/r16, verified)
// ---------------------------------------------------------------------------
__global__ __launch_bounds__(256)
void prepA_kernel(const float* __restrict__ Wl, const float* __restrict__ Wr,
                  const float* __restrict__ Wp,
                  const float* __restrict__ bl, const float* __restrict__ bp,
                  unsigned short* __restrict__ WlpB, unsigned short* __restrict__ WrpB,
                  float* __restrict__ cvec,
                  const int* __restrict__ ea, int Ea,
                  const int* __restrict__ eb, int Eb,
                  unsigned int* __restrict__ ent_a, int* __restrict__ cnt_a,
                  unsigned int* __restrict__ ent_b, int* __restrict__ cnt_b,
                  int NBKT, int CAP, int GA)
{
    __shared__ float wm[128 * 129];   // wprod branch
    __shared__ float wpc[128 * 16];
    __shared__ int hist[512];         // prep branch
    __shared__ int base[512];

    const int bid = blockIdx.x;
    const int t   = threadIdx.x;

    if (bid < 16) {
        const int m   = bid >> 3;
        const int cg  = bid & 7;
        const int c0  = cg * 16;
        const float* Wm = m ? Wr : Wl;
        unsigned short* OB = m ? WrpB : WlpB;

        for (int i = t; i < 128 * 128; i += 256) {
            int r = i >> 7, k = i & 127;
            wm[r * 129 + k] = Wm[i];
        }
        for (int i = t; i < 2048; i += 256) {
            int k = i >> 4, col = i & 15;
            wpc[i] = Wp[k * 128 + c0 + col];
        }
        __syncthreads();

        const int r = t >> 1;
        const int h = (t & 1) * 8;
        float acc[8];
        #pragma unroll
        for (int j = 0; j < 8; ++j) acc[j] = 0.f;

        for (int k = 0; k < 128; ++k) {
            float wv = wm[r * 129 + k];
            #pragma unroll
            for (int j = 0; j < 8; ++j) acc[j] += wv * wpc[k * 16 + h + j];
        }

        const int kt = r >> 5, lhi = (r >> 3) & 3, jj = r & 7;
        #pragma unroll
        for (int j = 0; j < 8; ++j) {
            int l = lhi * 16 + h + j;
            OB[((size_t)(kt * 8 + cg) * 64 + l) * 8 + jj] = f2bf(acc[j]);
        }

        if (m == 0 && t < 16) {
            int c = c0 + t;
            float s = bp[c];
            for (int k = 0; k < 128; ++k) s += bl[k] * wpc[k * 16 + t];
            cvec[c] = s;
        }
    } else {
        const int pb   = bid - 16;
        const int type = (pb >= GA);
        const int* e   = type ? eb : ea;
        const int  E   = type ? Eb : Ea;
        unsigned int* ent = type ? ent_b : ent_a;
        int* cnt          = type ? cnt_b : cnt_a;
        const int i0 = (pb - type * GA) * TILE;

        for (int h = t; h < NBKT; h += 256) hist[h] = 0;
        __syncthreads();

        int tgts[16];
        #pragma unroll
        for (int j = 0; j < 16; ++j) {
            int i = i0 + j * 256 + t;
            tgts[j] = (i < E) ? e[(size_t)E + i] : -1;
            if (tgts[j] >= 0) atomicAdd(&hist[tgts[j] >> 7], 1);
        }
        __syncthreads();

        for (int h = t; h < NBKT; h += 256) {
            base[h] = (hist[h] > 0) ? atomicAdd(&cnt[h], hist[h]) : 0;
            hist[h] = 0;
        }
        __syncthreads();

        #pragma unroll
        for (int j = 0; j < 16; ++j) {
            int i = i0 + j * 256 + t;
            if (tgts[j] >= 0) {
                int b   = tgts[j] >> 7;
                int pos = base[b] + atomicAdd(&hist[b], 1);
                if (pos < CAP)
                    ent[(size_t)b * CAP + pos] = ((unsigned)e[i] << 7) | (tgts[j] & 127);
            }
        }
    }
}

// ---------------------------------------------------------------------------
// Kernel B: sort (blocks 0..2*NBKT-1) || gemmz (rest). (r15/r16, verified)
// ---------------------------------------------------------------------------
__global__ __launch_bounds__(512)
void sortB_kernel(const unsigned int* __restrict__ ent_a, const int* __restrict__ cnt_a,
                  const unsigned int* __restrict__ ent_b, const int* __restrict__ cnt_b,
                  unsigned short* __restrict__ srcl_g, int* __restrict__ off_g,
                  const float* __restrict__ x,
                  const unsigned short* __restrict__ WlpB,
                  const unsigned short* __restrict__ WrpB,
                  const float* __restrict__ cvec,
                  unsigned short* __restrict__ zl, unsigned short* __restrict__ zr,
                  int N, int NBKT, int CAP)
{
    extern __shared__ __align__(16) char smem_raw[];

    const int bid = blockIdx.x;
    const int t   = threadIdx.x;

    if (bid < 2 * NBKT) {
        int* tmp  = (int*)smem_raw;                          // CAP
        int* off  = tmp + CAP;                               // BT+1
        int* cur  = off + BT + 1;                            // BT
        int* wtot = cur + BT;                                // 2
        unsigned short* srcl = (unsigned short*)(wtot + 2);  // CAP

        const int type = (bid >= NBKT);
        const int k    = bid - type * NBKT;
        const unsigned int* ent = type ? ent_b : ent_a;
        const int cnt = min((type ? cnt_b : cnt_a)[k], CAP);
        const int l = t & 63, w = t >> 6;

        if (t < BT) off[t] = 0;
        __syncthreads();

        for (int i = t; i < cnt; i += 512) {
            unsigned e = ent[(size_t)k * CAP + i];
            tmp[i] = (int)e;
            atomicAdd(&off[e & (BT - 1)], 1);
        }
        __syncthreads();

        int v = 0, s = 0;
        if (t < BT) {
            v = off[t]; s = v;
            #pragma unroll
            for (int o = 1; o < 64; o <<= 1) {
                int u = __shfl_up(s, o, 64);
                if (l >= o) s += u;
            }
            if (l == 63) wtot[w] = s;
        }
        __syncthreads();
        if (t < BT) {
            int ex = ((w == 1) ? wtot[0] : 0) + s - v;
            off[t] = ex; cur[t] = ex;
        }
        if (t == 0) off[BT] = wtot[0] + wtot[1];
        __syncthreads();

        for (int i = t; i < cnt; i += 512) {
            unsigned e = (unsigned)tmp[i];
            int pos = atomicAdd(&cur[e & (BT - 1)], 1);
            srcl[pos] = (unsigned short)(e >> 7);
        }
        __syncthreads();

        for (int i = t; i < cnt; i += 512)
            srcl_g[(size_t)bid * CAP + i] = srcl[i];
        if (t <= BT)
            off_g[(size_t)bid * (BT + 1) + t] = off[t];
    } else {
        const int gb = bid - 2 * NBKT;
        const int w = t >> 6, l = t & 63;
        const int q = l & 15, kg = l >> 4;
        const int node0 = gb * 128 + w * 16;
        const int arow = min(node0 + q, N - 1);

        const float4* xp = reinterpret_cast<const float4*>(x + (size_t)arow * D);
        bf16x8 fx[4];
        #pragma unroll
        for (int kt = 0; kt < 4; ++kt) {
            float4 a = xp[kt * 8 + kg * 2];
            float4 b = xp[kt * 8 + kg * 2 + 1];
            bf16x8 f;
            f[0] = (short)f2bf(a.x); f[1] = (short)f2bf(a.y);
            f[2] = (short)f2bf(a.z); f[3] = (short)f2bf(a.w);
            f[4] = (short)f2bf(b.x); f[5] = (short)f2bf(b.y);
            f[6] = (short)f2bf(b.z); f[7] = (short)f2bf(b.w);
            fx[kt] = f;
        }

        #pragma unroll
        for (int nt = 0; nt < 8; ++nt) {
            f32x4 cl = {0.f, 0.f, 0.f, 0.f};
            f32x4 cr = {0.f, 0.f, 0.f, 0.f};
            #pragma unroll
            for (int kt = 0; kt < 4; ++kt) {
                const size_t fo = ((size_t)(kt * 8 + nt) * 64 + l) * 8;
                bf16x8 wl = *reinterpret_cast<const bf16x8*>(WlpB + fo);
                bf16x8 wr = *reinterpret_cast<const bf16x8*>(WrpB + fo);
                cl = MFMA16(fx[kt], wl, cl, 0, 0, 0);
                cr = MFMA16(fx[kt], wr, cr, 0, 0, 0);
            }
            float cv = cvec[nt * 16 + q];
            const int sidx = nt >> 1;
            const int cin  = (nt & 1) * 16 + q;
            #pragma unroll
            for (int r = 0; r < 4; ++r) {
                int grow = node0 + kg * 4 + r;
                if (grow < N) {
                    zl[((size_t)sidx * (N + 1) + grow) * 32 + cin] = f2bf(cl[r]);
                    zr[(size_t)grow * D + nt * 16 + q]             = f2bf(cr[r] + cv);
                }
            }
        }
    }
}

// ---------------------------------------------------------------------------
// gather (r16 verbatim — best verified: 65.7us, 73% occupancy, 134.6 total):
// two-level BTS=32 sub-buckets, one target per 8-lane group, CE=128
// double-buffer (16.9 KB LDS -> ~8 blocks/CU), counted vmcnt(2),
// global_load_lds staging, slice=bid&3 XCD L2 residency (FETCH ~22MB).
// Floor analysis (r9-r17): 1.6M edges x 256B / 16B-per-lane = 25.6M
// address-divergent L1 lookups ÷ 256 CU ÷ 2.4GHz ≈ 42us ideal; observed
// 63-66us = x1.5 segment-skew — invariant to VALU/barrier/pipeline changes.
// ---------------------------------------------------------------------------
__global__ __launch_bounds__(256)
void gather_kernel(const unsigned short* __restrict__ zl,   // [4][N+1][32]
                   const unsigned short* __restrict__ srcl_g,
                   const int* __restrict__ off_g,
                   unsigned short* __restrict__ agg_a,
                   unsigned short* __restrict__ agg_b,
                   int N, int NBKT, int CAP)
{
    __shared__ int off[BTS + 1];
    __shared__ unsigned short stage[2][CE * 32];   // 2 x 8 KB

    const int bid   = blockIdx.x;
    const int slice = bid & 3;
    const int rest  = bid >> 2;
    const int sb    = rest & 3;                // sub-bucket 0..3
    const int tb    = rest >> 2;               // (type, k128)
    const int type  = (tb >= NBKT);
    const int k     = tb - type * NBKT;

    const int t = threadIdx.x, l = t & 63, w = t >> 6;
    const int tg = l >> 3;                     // group 0..7
    const int c8 = l & 7;                      // uint2 within 64B row

    for (int i = t; i <= BTS; i += 256)
        off[i] = off_g[(size_t)tb * (BT + 1) + sb * BTS + i];
    __syncthreads();

    const int base0 = off[0];
    const int cnt   = off[BTS] - base0;
    const unsigned short* zs = zl + (size_t)slice * (N + 1) * 32;
    const unsigned short* sl = srcl_g + (size_t)tb * CAP;

    const int tt = w * 8 + tg;                 // my single target (0..31)
    const int o0 = off[tt], o1 = off[tt + 1];
    f32x2 aP = {0.f, 0.f}, aQ = {0.f, 0.f};

    const int nc = (cnt + CE - 1) / CE;

#define STAGE(cc, bb)                                                         \
    {                                                                         \
        const int _c0 = base0 + (cc) * CE;                                    \
        _Pragma("unroll")                                                     \
        for (int i = 0; i < 2; ++i) {                                         \
            const int el = w * 32 + i * 16 + (l >> 2);                        \
            const unsigned sid = sl[_c0 + el];                                \
            const char* g = (const char*)zs + (size_t)sid * 64 + (l & 3) * 16;\
            char* ldsb = (char*)stage[bb] + (size_t)(w * 32 + i * 16) * 64;   \
            __builtin_amdgcn_global_load_lds(                                 \
                (const __attribute__((address_space(1))) unsigned*)g,         \
                (__attribute__((address_space(3))) unsigned*)ldsb, 16, 0, 0); \
        }                                                                     \
    }

    if (nc > 0) STAGE(0, 0);

    for (int c = 0; c < nc; ++c) {
        if (c + 1 < nc) {
            STAGE(c + 1, (c + 1) & 1);
            asm volatile("s_waitcnt vmcnt(2)" ::: "memory");
        } else {
            asm volatile("s_waitcnt vmcnt(0)" ::: "memory");
        }
        __builtin_amdgcn_s_barrier();
        asm volatile("" ::: "memory");

        const int c0 = base0 + c * CE;
        const unsigned short* sg = stage[c & 1];
        const int lo = max(o0, c0);
        const int hi = min(o1, c0 + CE);
        int j = lo;
        for (; j + 1 < hi; j += 2) {
            uint2 v0 = *reinterpret_cast<const uint2*>(sg + (j - c0) * 32 + c8 * 4);
            uint2 v1 = *reinterpret_cast<const uint2*>(sg + (j + 1 - c0) * 32 + c8 * 4);
            f32x2 p0, q0, p1, q1;
            p0[0] = __builtin_bit_cast(float, v0.x << 16);
            p0[1] = __builtin_bit_cast(float, v0.y << 16);
            q0[0] = __builtin_bit_cast(float, v0.x & 0xffff0000u);
            q0[1] = __builtin_bit_cast(float, v0.y & 0xffff0000u);
            p1[0] = __builtin_bit_cast(float, v1.x << 16);
            p1[1] = __builtin_bit_cast(float, v1.y << 16);
            q1[0] = __builtin_bit_cast(float, v1.x & 0xffff0000u);
            q1[1] = __builtin_bit_cast(float, v1.y & 0xffff0000u);
            aP += p0 + p1;
            aQ += q0 + q1;
        }
        if (j < hi) {
            uint2 v0 = *reinterpret_cast<const uint2*>(sg + (j - c0) * 32 + c8 * 4);
            f32x2 p0, q0;
            p0[0] = __builtin_bit_cast(float, v0.x << 16);
            p0[1] = __builtin_bit_cast(float, v0.y << 16);
            q0[0] = __builtin_bit_cast(float, v0.x & 0xffff0000u);
            q0[1] = __builtin_bit_cast(float, v0.y & 0xffff0000u);
            aP += p0;
            aQ += q0;
        }
        asm volatile("" ::: "memory");
        __builtin_amdgcn_s_barrier();   // stage[c&1] free before c+1 overwrites
    }
#undef STAGE

    unsigned short* agg = (type ? agg_b : agg_a) + (size_t)slice * N * 32;
    const int n = k * BT + sb * BTS + tt;
    const int deg = o1 - o0;
    if (n < N) {
        const float r = 1.0f / fmaxf((float)deg, 1.0f);
        uint2 o;
        o.x = ((unsigned)f2bf(aQ[0] * r) << 16) | f2bf(aP[0] * r);
        o.y = ((unsigned)f2bf(aQ[1] * r) << 16) | f2bf(aP[1] * r);
        *reinterpret_cast<uint2*>(agg + (size_t)n * 32 + c8 * 4) = o;
    }
}

// ---------------------------------------------------------------------------
// epilogue: logits_t = agg_t + Z_r; softmax, average, store f32. (verified r9)
// ---------------------------------------------------------------------------
__global__ __launch_bounds__(256)
void epi_kernel(const unsigned short* __restrict__ agg_a,
                const unsigned short* __restrict__ agg_b,
                const unsigned short* __restrict__ zr,
                float* __restrict__ out, int N)
{
    const int t = threadIdx.x;
    const int n = blockIdx.x * 16 + (t >> 4);
    const int c = t & 15;
    if (n >= N) return;

    const int s = c >> 2;
    const size_t aoff = ((size_t)s * N + n) * 32 + (c & 3) * 8;
    uint4 va = *reinterpret_cast<const uint4*>(agg_a + aoff);
    uint4 vb = *reinterpret_cast<const uint4*>(agg_b + aoff);
    uint4 vz = *reinterpret_cast<const uint4*>(zr + (size_t)n * D + c * 8);

    unsigned ua[4] = {va.x, va.y, va.z, va.w};
    unsigned ub[4] = {vb.x, vb.y, vb.z, vb.w};
    unsigned uz[4] = {vz.x, vz.y, vz.z, vz.w};

    float la[8], lb[8];
    #pragma unroll
    for (int d = 0; d < 4; ++d) {
        float z0 = __builtin_bit_cast(float, uz[d] << 16);
        float z1 = __builtin_bit_cast(float, uz[d] & 0xffff0000u);
        la[2*d]   = __builtin_bit_cast(float, ua[d] << 16) + z0;
        la[2*d+1] = __builtin_bit_cast(float, ua[d] & 0xffff0000u) + z1;
        lb[2*d]   = __builtin_bit_cast(float, ub[d] << 16) + z0;
        lb[2*d+1] = __builtin_bit_cast(float, ub[d] & 0xffff0000u) + z1;
    }

    float ma = -INFINITY, mb = -INFINITY;
    #pragma unroll
    for (int j = 0; j < 8; ++j) { ma = fmaxf(ma, la[j]); mb = fmaxf(mb, lb[j]); }
    #pragma unroll
    for (int o = 1; o < 16; o <<= 1) {
        ma = fmaxf(ma, __shfl_xor(ma, o, 64));
        mb = fmaxf(mb, __shfl_xor(mb, o, 64));
    }
    float sa = 0.f, sb = 0.f;
    #pragma unroll
    for (int j = 0; j < 8; ++j) {
        la[j] = __expf(la[j] - ma); sa += la[j];
        lb[j] = __expf(lb[j] - mb); sb += lb[j];
    }
    #pragma unroll
    for (int o = 1; o < 16; o <<= 1) {
        sa += __shfl_xor(sa, o, 64);
        sb += __shfl_xor(sb, o, 64);
    }
    const float ra = 0.5f / sa, rb = 0.5f / sb;

    float4 o0, o1;
    o0.x = la[0]*ra + lb[0]*rb; o0.y = la[1]*ra + lb[1]*rb;
    o0.z = la[2]*ra + lb[2]*rb; o0.w = la[3]*ra + lb[3]*rb;
    o1.x = la[4]*ra + lb[4]*rb; o1.y = la[5]*ra + lb[5]*rb;
    o1.z = la[6]*ra + lb[6]*rb; o1.w = la[7]*ra + lb[7]*rb;
    float* op = out + (size_t)n * D + c * 8;
    *reinterpret_cast<float4*>(op)     = o0;
    *reinterpret_cast<float4*>(op + 4) = o1;
}

// ---------------------------------------------------------------------------
extern "C" void kernel_launch(void* const* d_in, const int* in_sizes, int n_in,
                              void* d_out, int out_size, void* d_ws, size_t ws_size,
                              hipStream_t stream)
{
    const float* x  = (const float*)d_in[0];
    const float* Wl = (const float*)d_in[1];
    const float* bl = (const float*)d_in[2];
    const float* Wr = (const float*)d_in[3];
    const float* Wp = (const float*)d_in[4];
    const float* bp = (const float*)d_in[5];
    const int*   ea = (const int*)d_in[6];
    const int*   eb = (const int*)d_in[7];

    const int N  = in_sizes[0] / D;
    const int Ea = in_sizes[6] / 2;
    const int Eb = in_sizes[7] / 2;

    const int NBKT = (N + BT - 1) / BT;          // 391 for N=50000
    const int Emax = Ea > Eb ? Ea : Eb;
    int CAP = (int)(((long long)Emax * BT / N) * 5 / 4 + 128);   // ~2688
    CAP = (CAP + 7) & ~7;

    unsigned int* ent_a = (unsigned int*)d_ws;              // NBKT*CAP
    unsigned int* ent_b = ent_a + (size_t)NBKT * CAP;
    int* cnt_a = (int*)(ent_b + (size_t)NBKT * CAP);        // NBKT
    int* cnt_b = cnt_a + NBKT;
    int* off_g = cnt_b + NBKT;                              // 2*NBKT*(BT+1)
    float* cvec = (float*)(off_g + (size_t)2 * NBKT * (BT + 1));  // 128
    uintptr_t p = (uintptr_t)(cvec + 128);
    p = (p + 15) & ~(uintptr_t)15;
    unsigned short* srcl_g = (unsigned short*)p;            // 2*NBKT*CAP + slack
    unsigned short* zl     = srcl_g + (size_t)2 * NBKT * CAP + 1024; // [4][N+1][32]
    unsigned short* zr     = zl + (size_t)4 * (N + 1) * 32;
    unsigned short* agg_a  = zr + (size_t)N * D;            // [4][N][32]
    unsigned short* agg_b  = agg_a + (size_t)N * D;
    unsigned short* WlpB   = agg_b + (size_t)N * D;
    unsigned short* WrpB   = WlpB + D * D;

    hipMemsetAsync(cnt_a, 0, sizeof(int) * 2 * (size_t)NBKT, stream);

    const int GA = (Ea + TILE - 1) / TILE;
    const int GB = (Eb + TILE - 1) / TILE;

    // Kernel A: wprod (16 blocks) || prep (GA+GB blocks)
    prepA_kernel<<<16 + GA + GB, 256, 0, stream>>>(
        Wl, Wr, Wp, bl, bp, WlpB, WrpB, cvec,
        ea, Ea, eb, Eb, ent_a, cnt_a, ent_b, cnt_b, NBKT, CAP, GA);

    // Kernel B: sort (2*NBKT blocks) || gemmz (ceil(N/128) blocks)
    const int GZ = (N + 127) / 128;
    const int smem_sort = CAP * 6 + (BT + 1 + BT + 2) * 4 + 16;
    sortB_kernel<<<2 * NBKT + GZ, 512, smem_sort, stream>>>(
        ent_a, cnt_a, ent_b, cnt_b, srcl_g, off_g,
        x, WlpB, WrpB, cvec, zl, zr, N, NBKT, CAP);

    // gather: 2*NBKT buckets x 4 sub-buckets x 4 slices; slice = bid&3
    gather_kernel<<<2 * NBKT * 4 * 4, 256, 0, stream>>>(
        zl, srcl_g, off_g, agg_a, agg_b, N, NBKT, CAP);

    epi_kernel<<<(N + 15) / 16, 256, 0, stream>>>(agg_a, agg_b, zr,
                                                  (float*)d_out, N);
}